// Round 1
// baseline (292.596 us; speedup 1.0000x reference)
//
#include <hip/hip_runtime.h>
#include <math.h>

// Direct 3x3 conv, fp32, LDS-tiled.
// Block: 256 threads = 4 waves. Each wave owns one filter-group of 8 filters.
// Within a wave: tx = lane&7 (8 pixels each along x), ty = lane>>3 (row 0..7).
// Block output tile: 8 rows x 64 cols x 32 filters for one batch image.
// Input staged in 2 channel-chunks of 8 channels (halo 10 rows x 66 cols,
// row stride padded to 68 floats so every row is 16B-aligned for b128 reads).
// LDS: 8*10*68*4 = 21760 B input + 144*32*4 = 18432 B weights = 39.3 KiB
//   -> 4 blocks/CU, 16 waves/CU with __launch_bounds__(256,4).

#define BLOCK 256
#define TW 64
#define TH 8
#define CCHUNK 8
#define ROWS (TH + 2)      // 10
#define COLS 66            // logical halo width
#define COLS_PAD 68        // padded stride: 68*4B = 272B = 16B-aligned rows

__device__ __forceinline__ float sigf(float z) {
    return 1.0f / (1.0f + __expf(-z));
}

extern "C" __global__ __launch_bounds__(BLOCK, 4)
void conv3x3_f32(const float* __restrict__ xin,
                 const float* __restrict__ wgt,
                 const float* __restrict__ bias,
                 float* __restrict__ out) {
    __shared__ float sIn[CCHUNK * ROWS * COLS_PAD]; // 5440 floats
    __shared__ float sW[144 * 32];                  // 4608 floats

    const int tid  = threadIdx.x;
    const int fg   = tid >> 6;     // filter group 0..3 (one per wave)
    const int lane = tid & 63;
    const int tx   = lane & 7;     // 8 pixels each -> 64 cols
    const int ty   = lane >> 3;    // 0..7 rows

    const int x0 = blockIdx.x * TW;
    const int y0 = blockIdx.y * TH;
    const int b  = blockIdx.z;

    // stage all weights once (k-major layout matches input: w[k*32+f])
    for (int i = tid; i < 144 * 32; i += BLOCK) sW[i] = wgt[i];

    float acc[8][8];
    #pragma unroll
    for (int p = 0; p < 8; ++p)
        #pragma unroll
        for (int f = 0; f < 8; ++f) acc[p][f] = 0.0f;

    for (int cc = 0; cc < 2; ++cc) {
        if (cc) __syncthreads();   // protect LDS reuse across chunks
        // stage 8 channels: rows y0-1..y0+8, cols x0-1..x0+64, zero-pad OOB
        for (int i = tid; i < CCHUNK * ROWS * COLS; i += BLOCK) {
            int c   = i / (ROWS * COLS);
            int rem = i - c * (ROWS * COLS);
            int r   = rem / COLS;
            int col = rem - r * COLS;
            int gy = y0 - 1 + r;
            int gx = x0 - 1 + col;
            float v = 0.0f;
            if ((unsigned)gy < 256u && (unsigned)gx < 256u)
                v = xin[(((b * 16) + cc * CCHUNK + c) * 256 + gy) * 256 + gx];
            sIn[(c * ROWS + r) * COLS_PAD + col] = v;
        }
        __syncthreads();

        #pragma unroll 1   // keep I$ footprint sane; dy body below is ~600 insts
        for (int c = 0; c < CCHUNK; ++c) {
            #pragma unroll
            for (int dy = 0; dy < 3; ++dy) {
                // input row segment: lds cols tx*8 .. tx*8+9 (16B-aligned base)
                const float* rowp = &sIn[(c * ROWS + ty + dy) * COLS_PAD + tx * 8];
                float4 s0 = *(const float4*)(rowp);
                float4 s1 = *(const float4*)(rowp + 4);
                float  s8 = rowp[8];
                float  s9 = rowp[9];
                float seg[10] = {s0.x, s0.y, s0.z, s0.w,
                                 s1.x, s1.y, s1.z, s1.w, s8, s9};
                // weights for (c, dy, dx=0..2, f = fg*8..fg*8+7): broadcast reads
                const float* wp = &sW[((cc * CCHUNK + c) * 9 + dy * 3) * 32 + fg * 8];
                float4 wA0 = *(const float4*)(wp +  0);
                float4 wA1 = *(const float4*)(wp +  4);
                float4 wB0 = *(const float4*)(wp + 32);
                float4 wB1 = *(const float4*)(wp + 36);
                float4 wC0 = *(const float4*)(wp + 64);
                float4 wC1 = *(const float4*)(wp + 68);
                float wv[3][8] = {
                    {wA0.x, wA0.y, wA0.z, wA0.w, wA1.x, wA1.y, wA1.z, wA1.w},
                    {wB0.x, wB0.y, wB0.z, wB0.w, wB1.x, wB1.y, wB1.z, wB1.w},
                    {wC0.x, wC0.y, wC0.z, wC0.w, wC1.x, wC1.y, wC1.z, wC1.w},
                };
                #pragma unroll
                for (int dx = 0; dx < 3; ++dx)
                    #pragma unroll
                    for (int p = 0; p < 8; ++p)
                        #pragma unroll
                        for (int f = 0; f < 8; ++f)
                            acc[p][f] += seg[p + dx] * wv[dx][f];
            }
        }
    }

    // epilogue: out = sigmoid(acc + bias[f,y,x]); coalesced float4 stores
    const int gy = y0 + ty;
    const int gx = x0 + tx * 8;
    #pragma unroll
    for (int f = 0; f < 8; ++f) {
        const int fglob = fg * 8 + f;
        const float* bp = &bias[(fglob * 256 + gy) * 256 + gx];
        float*       op = &out [((b * 32 + fglob) * 256 + gy) * 256 + gx];
        float4 b0 = *(const float4*)(bp);
        float4 b1 = *(const float4*)(bp + 4);
        float4 o0, o1;
        o0.x = sigf(acc[0][f] + b0.x);
        o0.y = sigf(acc[1][f] + b0.y);
        o0.z = sigf(acc[2][f] + b0.z);
        o0.w = sigf(acc[3][f] + b0.w);
        o1.x = sigf(acc[4][f] + b1.x);
        o1.y = sigf(acc[5][f] + b1.y);
        o1.z = sigf(acc[6][f] + b1.z);
        o1.w = sigf(acc[7][f] + b1.w);
        *(float4*)(op)     = o0;
        *(float4*)(op + 4) = o1;
    }
}

extern "C" void kernel_launch(void* const* d_in, const int* in_sizes, int n_in,
                              void* d_out, int out_size, void* d_ws, size_t ws_size,
                              hipStream_t stream) {
    const float* x    = (const float*)d_in[0];   // (16,16,256,256) fp32
    const float* w    = (const float*)d_in[1];   // (144,32) fp32, k-major
    const float* bias = (const float*)d_in[2];   // (32,256,256) fp32
    float* out = (float*)d_out;                  // (16,32,256,256) fp32

    dim3 grid(256 / TW, 256 / TH, 16);           // (4, 32, 16) = 2048 blocks
    conv3x3_f32<<<grid, dim3(BLOCK), 0, stream>>>(x, w, bias, out);
}

// Round 2
// 282.342 us; speedup vs baseline: 1.0363x; 1.0363x over previous
//
#include <hip/hip_runtime.h>
#include <math.h>

// Direct 3x3 conv, fp32, LDS-tiled — round 2: register-pressure fix.
// Block: 256 threads = 4 waves; wave w owns filters w*8..w*8+7.
// Lane: tx = lane&7 (8 px along x), ty = lane>>3 (row 0..7).
// Block tile: 8 rows x 64 cols x 32 filters, one batch image.
// Weights are NOT staged in LDS: they are read via wave-uniform addresses
// (readfirstlane-forced) from a const __restrict__ pointer -> SMEM s_load,
// living in SGPRs. Frees 24 VGPRs + 6 LDS reads per (c,dy) epoch.
// LDS: input tile only, 8ch x 10rows x 68 floats = 21760 B.
// __launch_bounds__(256,4): 128-VGPR cap; est. live ~91 -> acc stays in VGPRs.

#define BLOCK 256
#define TW 64
#define TH 8
#define CCHUNK 8
#define ROWS (TH + 2)      // 10
#define COLS 66            // logical halo width
#define COLS_PAD 68        // padded stride: rows 16B-aligned for b128

__device__ __forceinline__ float sigf(float z) {
    return 1.0f / (1.0f + __expf(-z));
}

extern "C" __global__ __launch_bounds__(BLOCK, 4)
void conv3x3_f32(const float* __restrict__ xin,
                 const float* __restrict__ wgt,
                 const float* __restrict__ bias,
                 float* __restrict__ out) {
    __shared__ float sIn[CCHUNK * ROWS * COLS_PAD]; // 5440 floats = 21760 B

    const int tid  = threadIdx.x;
    // wave-uniform filter group -> SGPR; enables SMEM weight loads
    const int fgu  = __builtin_amdgcn_readfirstlane(tid >> 6);
    const int lane = tid & 63;
    const int tx   = lane & 7;
    const int ty   = lane >> 3;

    const int x0 = blockIdx.x * TW;
    const int y0 = blockIdx.y * TH;
    const int b  = blockIdx.z;

    // uniform base for this wave's 8 filters (k-major: wgt[k*32 + f])
    const float* __restrict__ wb = wgt + fgu * 8;

    float acc[8][8];
    #pragma unroll
    for (int p = 0; p < 8; ++p)
        #pragma unroll
        for (int f = 0; f < 8; ++f) acc[p][f] = 0.0f;

    for (int cc = 0; cc < 2; ++cc) {
        if (cc) __syncthreads();   // protect LDS reuse across chunks
        // stage 8 channels: rows y0-1..y0+8, cols x0-1..x0+64, zero-pad OOB
        for (int i = tid; i < CCHUNK * ROWS * COLS; i += BLOCK) {
            int c   = i / (ROWS * COLS);
            int rem = i - c * (ROWS * COLS);
            int r   = rem / COLS;
            int col = rem - r * COLS;
            int gy = y0 - 1 + r;
            int gx = x0 - 1 + col;
            float v = 0.0f;
            if ((unsigned)gy < 256u && (unsigned)gx < 256u)
                v = xin[(((b * 16) + cc * CCHUNK + c) * 256 + gy) * 256 + gx];
            sIn[(c * ROWS + r) * COLS_PAD + col] = v;
        }
        __syncthreads();

        #pragma unroll 1   // keep I$ footprint ~2.7KB; dy body below unrolled
        for (int c = 0; c < CCHUNK; ++c) {
            #pragma unroll
            for (int dy = 0; dy < 3; ++dy) {
                // weights for (c,dy): 3 taps x 8 filters, wave-uniform -> s_load
                const float* wp = wb + ((cc * CCHUNK + c) * 9 + dy * 3) * 32;
                float w0[8], w1[8], w2[8];
                #pragma unroll
                for (int j = 0; j < 8; ++j) {
                    w0[j] = wp[j];
                    w1[j] = wp[32 + j];
                    w2[j] = wp[64 + j];
                }
                // input row segment: 12 floats (10 used), 3x ds_read_b128
                const float* rowp = &sIn[(c * ROWS + ty + dy) * COLS_PAD + tx * 8];
                float4 s0 = *(const float4*)(rowp);
                float4 s1 = *(const float4*)(rowp + 4);
                float4 s2 = *(const float4*)(rowp + 8);
                float seg[12] = {s0.x, s0.y, s0.z, s0.w,
                                 s1.x, s1.y, s1.z, s1.w,
                                 s2.x, s2.y, s2.z, s2.w};
                #pragma unroll
                for (int p = 0; p < 8; ++p)
                    #pragma unroll
                    for (int f = 0; f < 8; ++f)
                        acc[p][f] = fmaf(seg[p + 2], w2[f],
                                     fmaf(seg[p + 1], w1[f],
                                      fmaf(seg[p], w0[f], acc[p][f])));
            }
        }
    }

    // epilogue: out = sigmoid(acc + bias[f,y,x]); coalesced float4 stores
    const int gy = y0 + ty;
    const int gx = x0 + tx * 8;
    #pragma unroll
    for (int f = 0; f < 8; ++f) {
        const int fglob = fgu * 8 + f;
        const float* bp = &bias[(fglob * 256 + gy) * 256 + gx];
        float*       op = &out [((b * 32 + fglob) * 256 + gy) * 256 + gx];
        float4 b0 = *(const float4*)(bp);
        float4 b1 = *(const float4*)(bp + 4);
        float4 o0, o1;
        o0.x = sigf(acc[0][f] + b0.x);
        o0.y = sigf(acc[1][f] + b0.y);
        o0.z = sigf(acc[2][f] + b0.z);
        o0.w = sigf(acc[3][f] + b0.w);
        o1.x = sigf(acc[4][f] + b1.x);
        o1.y = sigf(acc[5][f] + b1.y);
        o1.z = sigf(acc[6][f] + b1.z);
        o1.w = sigf(acc[7][f] + b1.w);
        *(float4*)(op)     = o0;
        *(float4*)(op + 4) = o1;
    }
}

extern "C" void kernel_launch(void* const* d_in, const int* in_sizes, int n_in,
                              void* d_out, int out_size, void* d_ws, size_t ws_size,
                              hipStream_t stream) {
    const float* x    = (const float*)d_in[0];   // (16,16,256,256) fp32
    const float* w    = (const float*)d_in[1];   // (144,32) fp32, k-major
    const float* bias = (const float*)d_in[2];   // (32,256,256) fp32
    float* out = (float*)d_out;                  // (16,32,256,256) fp32

    dim3 grid(256 / TW, 256 / TH, 16);           // (4, 32, 16) = 2048 blocks
    conv3x3_f32<<<grid, dim3(BLOCK), 0, stream>>>(x, w, bias, out);
}

// Round 3
// 211.802 us; speedup vs baseline: 1.3815x; 1.3330x over previous
//
#include <hip/hip_runtime.h>
#include <math.h>

// Round 3: fp16 MFMA im2col conv.
// D[32 filters x 32 pixels] per wave-tile via v_mfma_f32_32x32x16_f16,
// A = weights (M=filters), B = pixels (N) -> C/D col (lane&31) = pixel x,
// giving coalesced epilogue loads/stores.
// K = 144 = 9 taps x 16 channels: exactly 9 MFMAs per tile, K-slice = one
// tap's 16 channels. fp32 accumulation; only input fp16 quantization error
// (est. absmax ~1e-2 < 2e-2 threshold).
// LDS: input halo tile channel-last fp16 [10][66][16] = 21120 B.
//  - B-fragment: lane reads 8 contiguous channels = one ds_read_b128.
//  - staging: (c-pair = lane&7, col = lane>>3) -> 32 distinct banks/wave.
// Block: 256 thr = 4 waves; tile 8 rows x 64 cols x 32 filters, one image.
// Per wave: 4 pixel-tiles (rows 2w..2w+1, col-halves 0..1), 9 MFMA each.

typedef __attribute__((ext_vector_type(8)))  _Float16 half8;
typedef __attribute__((ext_vector_type(2)))  _Float16 half2v;
typedef __attribute__((ext_vector_type(16))) float    float16v;

#define BLOCK 256
#define TW 64
#define TH 8
#define HROWS 10
#define HCOLS 66

__device__ __forceinline__ float sigf(float z) {
    return 1.0f / (1.0f + __expf(-z));
}

extern "C" __global__ __launch_bounds__(BLOCK, 4)
void conv3x3_mfma(const float* __restrict__ xin,
                  const float* __restrict__ wgt,
                  const float* __restrict__ bias,
                  float* __restrict__ out) {
    __shared__ _Float16 sIn[HROWS * HCOLS * 16];   // [r][col][c], 21120 B

    const int tid = threadIdx.x;
    const int x0 = blockIdx.x * TW;
    const int y0 = blockIdx.y * TH;
    const int b  = blockIdx.z;

    // ---- stage input halo: fp32 NCHW -> fp16 LDS [row][col][channel]
    // pair-index p: c2 = p&7 (channel pair), colr = p>>3 -> (r, col)
    for (int p = tid; p < HROWS * HCOLS * 8; p += BLOCK) {
        int c2   = p & 7;
        int colr = p >> 3;
        int r    = colr / HCOLS;          // magic-div
        int col  = colr - r * HCOLS;
        int gy = y0 - 1 + r;
        int gx = x0 - 1 + col;
        float v0 = 0.0f, v1 = 0.0f;
        if ((unsigned)gy < 256u && (unsigned)gx < 256u) {
            const float* px = &xin[((b * 16 + 2 * c2) * 256 + gy) * 256 + gx];
            v0 = px[0];
            v1 = px[256 * 256];           // next channel plane
        }
        half2v hv = { (_Float16)v0, (_Float16)v1 };
        *(half2v*)&sIn[(r * HCOLS + col) * 16 + 2 * c2] = hv;  // 4B, bank-clean
    }

    // ---- preload weight A-fragments: 9 taps x 8 channels (per lane)
    // A[m][k]: m = lane&31 = filter, k = (lane>>5)*8 + j = channel
    // wgt layout: [c*9 + tap][filter] (torch Unfold row order c,kh,kw)
    const int lane = tid & 63;
    const int f    = lane & 31;
    const int kg   = lane >> 5;
    half8 wfrag[9];
    #pragma unroll
    for (int t = 0; t < 9; ++t) {
        #pragma unroll
        for (int j = 0; j < 8; ++j) {
            int c = kg * 8 + j;
            wfrag[t][j] = (_Float16)wgt[(c * 9 + t) * 32 + f];
        }
    }

    __syncthreads();

    const int wv = tid >> 6;      // wave id 0..3
    const int px = lane & 31;     // pixel-within-tile (B-operand n)

    #pragma unroll 1
    for (int t4 = 0; t4 < 4; ++t4) {
        const int r = wv * 2 + (t4 >> 1);   // output row within tile
        const int h = t4 & 1;               // col half
        float16v acc = {};                  // fp32 accumulator, zeroed

        #pragma unroll
        for (int dy = 0; dy < 3; ++dy) {
            #pragma unroll
            for (int dx = 0; dx < 3; ++dx) {
                const int rh = r + dy;              // halo row 0..9
                const int ch = h * 32 + px + dx;    // halo col 0..65
                half8 bfrag = *(const half8*)&sIn[(rh * HCOLS + ch) * 16 + kg * 8];
                acc = __builtin_amdgcn_mfma_f32_32x32x16_f16(
                          wfrag[dy * 3 + dx], bfrag, acc, 0, 0, 0);
            }
        }

        // ---- epilogue: C/D row = filter = (reg&3) + 8*(reg>>2) + 4*kg,
        // col = pixel = px. Lanes 0..31 are consecutive x -> coalesced.
        const int y  = y0 + r;
        const int xg = x0 + h * 32 + px;
        #pragma unroll
        for (int reg = 0; reg < 16; ++reg) {
            const int ff = (reg & 3) + 8 * (reg >> 2) + 4 * kg;
            const float bz = bias[(ff * 256 + y) * 256 + xg];
            out[((b * 32 + ff) * 256 + y) * 256 + xg] = sigf(acc[reg] + bz);
        }
    }
}

extern "C" void kernel_launch(void* const* d_in, const int* in_sizes, int n_in,
                              void* d_out, int out_size, void* d_ws, size_t ws_size,
                              hipStream_t stream) {
    const float* x    = (const float*)d_in[0];   // (16,16,256,256) fp32
    const float* w    = (const float*)d_in[1];   // (144,32) fp32
    const float* bias = (const float*)d_in[2];   // (32,256,256) fp32
    float* out = (float*)d_out;                  // (16,32,256,256) fp32

    dim3 grid(256 / TW, 256 / TH, 16);           // (4, 32, 16) = 2048 blocks
    conv3x3_mfma<<<grid, dim3(BLOCK), 0, stream>>>(x, w, bias, out);
}